// Round 12
// baseline (125.982 us; speedup 1.0000x reference)
//
#include <hip/hip_runtime.h>

#define N_NODES 100000
#define N_EDGES 1600000
#define N_LABEL 200000
#define HID 128
#define OUT 5

#define NBUCK 391        // ceil(N_NODES/256)
#define EPB   2048       // edges per partition block
#define NBLK_E 782       // ceil(N_EDGES/EPB)
#define PREC_BLKS 9      // ceil(129*16/256) precomp blocks appended to k_hist

// ---------------------------------------------------------------------------
// Linear network: out[l] = proj[d][0..4] + proj[p][5..9] + b_lin,
//   t[n]    = bf16( dinv_n * (x[n] @ G) )      (10 bf16, 32B row, L2-resident)
//   proj[n] = dinv_n * (sum_{src} t[src] + t[n]) + c0
// with G = W_gcn @ [W_lin_top | W_lin_bot] (128x10), c0 = b_gcn @ W2.
// ---------------------------------------------------------------------------

__device__ inline void bf2x(unsigned u, float& lo, float& hi) {
    lo = __uint_as_float(u << 16);
    hi = __uint_as_float(u & 0xffff0000u);
}
__device__ inline unsigned pack2(float a, float b) {
    unsigned ua = __float_as_uint(a), ub = __float_as_uint(b);
    ua = (ua + 0x7fffu + ((ua >> 16) & 1u)) >> 16;
    ub = (ub + 0x7fffu + ((ub >> 16) & 1u)) & 0xffff0000u;
    return ua | ub;
}

// ---------------------------------------------------------------------------
// K_hist (+ merged precomp): blocks < NBLK_E do the bucket histogram;
// blocks >= NBLK_E compute G[r][j] and the c0 row (row 128).
// ---------------------------------------------------------------------------
__global__ __launch_bounds__(256) void k_hist(const int* __restrict__ ei,
                                              int* __restrict__ hist,
                                              const float* __restrict__ Wg,
                                              const float* __restrict__ bg,
                                              const float* __restrict__ Wl,
                                              float* __restrict__ G) {
    const int t = threadIdx.x, b = blockIdx.x;
    if (b >= NBLK_E) {   // precomp path (whole block branches together)
        int o = (b - NBLK_E) * 256 + t;
        if (o < 129 * 16) {
            int r = o >> 4, jj = o & 15;
            float acc = 0.f;
            if (jj < 2 * OUT) {
                const int half = (jj >= OUT);
                const int j = half ? jj - OUT : jj;
                for (int c = 0; c < HID; ++c) {
                    float w2 = Wl[(half * HID + c) * OUT + j];
                    float a = (r < HID) ? Wg[r * HID + c] : bg[c];
                    acc += a * w2;
                }
            }
            G[o] = acc;
        }
        return;
    }
    __shared__ int h[NBUCK];
    for (int i = t; i < NBUCK; i += 256) h[i] = 0;
    __syncthreads();
    const int e0 = b * EPB;
#pragma unroll
    for (int i = 0; i < 8; ++i) {
        int e = e0 + i * 256 + t;
        if (e < N_EDGES) atomicAdd(&h[ei[N_EDGES + e] >> 8], 1);
    }
    __syncthreads();
    for (int i = t; i < NBUCK; i += 256) hist[i * NBLK_E + b] = h[i];
}

// ---------------------------------------------------------------------------
// K_scanb: per-bucket scan over 782 block entries + ATOMIC-TICKET bucket base
// (bases disjoint, order irrelevant) — replaces the single-block k_base.
// ---------------------------------------------------------------------------
__global__ __launch_bounds__(256) void k_scanb(int* __restrict__ hist,
                                               int* __restrict__ btot,
                                               int* __restrict__ bbase,
                                               int* __restrict__ total) {
    __shared__ int part[256];
    const int b = blockIdx.x, t = threadIdx.x;
    int* row = hist + b * NBLK_E;
    const int lo = t * 4, hi = min(lo + 4, NBLK_E);
    int v[4]; int s = 0;
    for (int i = lo; i < hi; ++i) { v[i - lo] = row[i]; s += v[i - lo]; }
    part[t] = s;
    __syncthreads();
#pragma unroll
    for (int off = 1; off < 256; off <<= 1) {
        int a = (t >= off) ? part[t - off] : 0;
        __syncthreads();
        part[t] += a;
        __syncthreads();
    }
    int run = part[t] - s;
    for (int i = lo; i < hi; ++i) { int x = v[i - lo]; row[i] = run; run += x; }
    if (t == 255) {
        int tot = part[255];
        btot[b] = tot;
        bbase[b] = atomicAdd(total, tot);   // disjoint range ticket
    }
}

// ---------------------------------------------------------------------------
// K_part: partition edges into bucket regions. bedge = src | (dst&255)<<20.
// ---------------------------------------------------------------------------
__global__ __launch_bounds__(256) void k_part(const int* __restrict__ ei,
                                              const int* __restrict__ hist,
                                              const int* __restrict__ bbase,
                                              unsigned* __restrict__ bedge) {
    __shared__ int cur[NBUCK];
    const int t = threadIdx.x, b = blockIdx.x;
    for (int i = t; i < NBUCK; i += 256) cur[i] = bbase[i] + hist[i * NBLK_E + b];
    __syncthreads();
    const int e0 = b * EPB;
#pragma unroll
    for (int i = 0; i < 8; ++i) {
        int e = e0 + i * 256 + t;
        if (e < N_EDGES) {
            int dst = ei[N_EDGES + e];
            unsigned src = (unsigned)ei[e];
            int pos = atomicAdd(&cur[dst >> 8], 1);
            bedge[pos] = src | ((unsigned)(dst & 255) << 20);
        }
    }
}

// ---------------------------------------------------------------------------
// K_build: per-bucket CSR (LDS count/scan/rank) -> csr, seg, dinv.
// ---------------------------------------------------------------------------
__global__ __launch_bounds__(256) void k_build(const unsigned* __restrict__ bedge,
                                               const int* __restrict__ bbase,
                                               const int* __restrict__ btot,
                                               int* __restrict__ csr,
                                               int2* __restrict__ seg,
                                               float* __restrict__ dinv) {
    __shared__ int cnt[256];
    __shared__ int nb[256];
    __shared__ int cursor[256];
    const int b = blockIdx.x, t = threadIdx.x;
    const int base = bbase[b];
    const int size = btot[b];
    cnt[t] = 0;
    __syncthreads();
    for (int i = t; i < size; i += 256) atomicAdd(&cnt[bedge[base + i] >> 20], 1);
    __syncthreads();
    const int c = cnt[t];
    nb[t] = c;
    __syncthreads();
#pragma unroll
    for (int off = 1; off < 256; off <<= 1) {
        int a = (t >= off) ? nb[t - off] : 0;
        __syncthreads();
        nb[t] += a;
        __syncthreads();
    }
    const int myBase = nb[t] - c;
    cursor[t] = myBase;
    __syncthreads();
    for (int i = t; i < size; i += 256) {
        unsigned v = bedge[base + i];
        int pos = atomicAdd(&cursor[v >> 20], 1);
        csr[base + pos] = (int)(v & 0xFFFFFu);
    }
    const int n = b * 256 + t;
    if (n < N_NODES) {
        seg[n] = make_int2(base + myBase, c);
        dinv[n] = rsqrtf((float)(c + 1));
    }
}

// ---------------------------------------------------------------------------
// K_t: t16[n] = bf16( dinv[n] * (x[n] @ G) ), row = 8 dwords (5 bf16-pairs + 0s).
//     16 lanes per node; coalesced x loads; G in LDS (stride 11, conflict-free).
// ---------------------------------------------------------------------------
__global__ __launch_bounds__(256) void k_t(const float* __restrict__ x,
                                           const float* __restrict__ G,
                                           const float* __restrict__ dinv,
                                           unsigned* __restrict__ t16) {
    __shared__ float Gs[HID * 11];
    const int tid = threadIdx.x;
    for (int o = tid; o < HID * 10; o += 256) {
        int k = o / 10, j = o - k * 10;
        Gs[k * 11 + j] = G[k * 16 + j];
    }
    __syncthreads();

    int gid = blockIdx.x * 256 + tid;
    int n = gid >> 4;
    int i = gid & 15;

    float xv[8];
#pragma unroll
    for (int m = 0; m < 8; ++m) xv[m] = x[(size_t)n * HID + i + 16 * m];

    float p[10];
#pragma unroll
    for (int j = 0; j < 10; ++j) p[j] = 0.f;
#pragma unroll
    for (int m = 0; m < 8; ++m) {
        const float* g = &Gs[(i + 16 * m) * 11];
#pragma unroll
        for (int j = 0; j < 10; ++j) p[j] += xv[m] * g[j];
    }
#pragma unroll
    for (int off = 1; off < 16; off <<= 1) {
#pragma unroll
        for (int j = 0; j < 10; ++j) p[j] += __shfl_xor(p[j], off);
    }
    // lane i<5 packs cols (2i, 2i+1); lanes 5-7 zero-pad; 8-15 idle
    float va = (i == 0) ? p[0] : (i == 1) ? p[2] : (i == 2) ? p[4] : (i == 3) ? p[6] : p[8];
    float vb = (i == 0) ? p[1] : (i == 1) ? p[3] : (i == 2) ? p[5] : (i == 3) ? p[7] : p[9];
    float di = dinv[n];
    if (i < 5)      t16[(size_t)n * 8 + i] = pack2(di * va, di * vb);
    else if (i < 8) t16[(size_t)n * 8 + i] = 0u;
}

// ---------------------------------------------------------------------------
// K_pullt: ONE WAVE per node. lane = e2*8 + i: 8 edge-slots x 8 lanes
//     (row = 32B). 64 csr entries loaded coalesced, shfl-broadcast; 8
//     predicated gathers in flight; self term on octet 0 only; 3-step
//     xor-fold across octets; lanes 0-4 write proj float2 pairs.
// ---------------------------------------------------------------------------
__global__ __launch_bounds__(256) void k_pullt(const unsigned* __restrict__ t16,
                                               const int2* __restrict__ seg,
                                               const int* __restrict__ csr,
                                               const float* __restrict__ dinv,
                                               const float* __restrict__ G,
                                               float* __restrict__ proj) {
    const int gid = blockIdx.x * 256 + threadIdx.x;
    const int n = gid >> 6;
    const int lane = gid & 63;
    const int e2 = lane >> 3;    // edge slot 0..7
    const int i = lane & 7;      // dword within row

    float aLo = 0.f, aHi = 0.f;
    if (e2 == 0) {   // self term once
        bf2x(t16[(size_t)n * 8 + i], aLo, aHi);
    }

    const int2 sg = seg[n];
    const int beg = sg.x, deg = sg.y;

    for (int base = 0; base < deg; base += 64) {
        const int cnt = min(64, deg - base);
        int myIdx = (lane < cnt) ? csr[beg + base + lane] : 0;
#pragma unroll
        for (int j = 0; j < 8; ++j) {
            int e = j * 8 + e2;
            int s = __shfl(myIdx, e);
            unsigned u = 0u;
            if (e < cnt) u = t16[(size_t)s * 8 + i];
            float lo, hi;
            bf2x(u, lo, hi);
            aLo += lo; aHi += hi;
        }
    }

    // fold the 8 octets together
    aLo += __shfl_xor(aLo, 8);  aHi += __shfl_xor(aHi, 8);
    aLo += __shfl_xor(aLo, 16); aHi += __shfl_xor(aHi, 16);
    aLo += __shfl_xor(aLo, 32); aHi += __shfl_xor(aHi, 32);

    if (lane < 5) {   // e2==0, i=lane: cols (2i, 2i+1)
        float di = dinv[n];
        float2 c0 = ((const float2*)(G + HID * 16))[lane];
        float2 r;
        r.x = di * aLo + c0.x;
        r.y = di * aHi + c0.y;
        *(float2*)&proj[(size_t)n * 16 + 2 * lane] = r;
    }
}

// ---------------------------------------------------------------------------
// K_link: out[l][o] = proj[d][o] + proj[p][5+o] + b_lin[o]
// ---------------------------------------------------------------------------
__global__ __launch_bounds__(256) void k_link2(const int* __restrict__ eli,
                                               const float* __restrict__ proj,
                                               const float* __restrict__ bl,
                                               float* __restrict__ out) {
    int t = blockIdx.x * 256 + threadIdx.x;
    int l = t >> 3, o = t & 7;
    if (l >= N_LABEL || o >= OUT) return;
    int d = eli[l];
    int p = eli[N_LABEL + l];
    out[l * OUT + o] = proj[d * 16 + o] + proj[p * 16 + OUT + o] + bl[o];
}

// ---------------------------------------------------------------------------
extern "C" void kernel_launch(void* const* d_in, const int* in_sizes, int n_in,
                              void* d_out, int out_size, void* d_ws, size_t ws_size,
                              hipStream_t stream) {
    const float* x     = (const float*)d_in[0];
    const int*   ei    = (const int*)d_in[1];
    const int*   eli   = (const int*)d_in[2];
    const float* W_gcn = (const float*)d_in[3];
    const float* b_gcn = (const float*)d_in[4];
    const float* W_lin = (const float*)d_in[5];
    const float* b_lin = (const float*)d_in[6];
    float* out = (float*)d_out;

    // workspace layout
    unsigned* t16    = (unsigned*)d_ws;                        // 100k x 8 u32 (3.2 MB)
    float* proj      = (float*)(t16 + (size_t)N_NODES * 8);    // 100k x 16 f32 (6.4 MB)
    float* G         = proj + (size_t)N_NODES * 16;            // 129*16 f32
    float* dinv      = G + 129 * 16;                           // 100k f32
    unsigned* bedge  = (unsigned*)(dinv + N_NODES);            // 1.6M u32 (6.4 MB)
    int*   csr       = (int*)(bedge + N_EDGES);                // 1.6M int (6.4 MB)
    int2*  seg       = (int2*)(csr + N_EDGES);                 // 100k int2
    int*   hist      = (int*)(seg + N_NODES);                  // 391*782 int
    int*   btot      = hist + NBUCK * NBLK_E;                  // 391 int
    int*   bbase     = btot + NBUCK;                           // 391 int
    int*   total     = bbase + NBUCK;                          // 1 int

    hipMemsetAsync(total, 0, sizeof(int), stream);

    // histogram + (merged) G/c0 precompute
    k_hist<<<NBLK_E + PREC_BLKS, 256, 0, stream>>>(ei, hist, W_gcn, b_gcn, W_lin, G);
    // per-bucket scan + atomic-ticket bases (k_base eliminated)
    k_scanb<<<NBUCK, 256, 0, stream>>>(hist, btot, bbase, total);
    // partition edges into buckets
    k_part<<<NBLK_E, 256, 0, stream>>>(ei, hist, bbase, bedge);
    // per-bucket CSR + seg + dinv
    k_build<<<NBUCK, 256, 0, stream>>>(bedge, bbase, btot, csr, seg, dinv);
    // t16 = bf16(dinv * x @ G)   (reads x once; 3.2 MB L2-resident table)
    k_t<<<N_NODES * 16 / 256, 256, 0, stream>>>(x, G, dinv, t16);
    // proj = dinv * (sum t[src] + t[n]) + c0   (wave per node, 8 edges/instr)
    k_pullt<<<N_NODES * 64 / 256, 256, 0, stream>>>(t16, seg, csr, dinv, G, proj);
    // out = gather-add
    k_link2<<<(N_LABEL * 8 + 255) / 256, 256, 0, stream>>>(eli, proj, b_lin, out);
}